// Round 4
// baseline (285.915 us; speedup 1.0000x reference)
//
#include <hip/hip_runtime.h>
#include <hip/hip_bf16.h>

static constexpr int B = 8;
static constexpr int C = 384;
static constexpr int H = 32;
static constexpr int W = 32;
static constexpr int N = 1024;      // H*W
static constexpr int Cg = 128;      // C/G
static constexpr int HEADS = 12;
static constexpr int BG = 24;       // B*G
static constexpr float SCALE = 0.17677669529663687f; // hc^-0.5

typedef short bf16x8 __attribute__((ext_vector_type(8)));
typedef float f32x4 __attribute__((ext_vector_type(4)));

__device__ __forceinline__ unsigned short bf16_bits(float x) {
    __hip_bfloat16 h = __float2bfloat16(x);
    return __builtin_bit_cast(unsigned short, h);
}

// ---------------------------------------------------------------------------
// prep: blocks 0..287 convert 4 weight matrices to bf16; blocks 288..1055
// transpose x1 fp32 [b][384][1024] -> bf16 token-major [b][1024][384].
// ---------------------------------------------------------------------------
__global__ __launch_bounds__(256) void prep(const float* __restrict__ wq,
                                            const float* __restrict__ wk,
                                            const float* __restrict__ wv,
                                            const float* __restrict__ wo,
                                            const float* __restrict__ x1,
                                            unsigned short* __restrict__ w16,
                                            unsigned short* __restrict__ x1T)
{
    __shared__ float tile[32][132];
    const int bx = blockIdx.x;
    const int tid = threadIdx.x;
    if (bx < 288) {
        int which = bx / 72, blk = bx - which*72;
        const float* src = (which == 0) ? wq : (which == 1) ? wk : (which == 2) ? wv : wo;
        int idx = (blk*256 + tid) * 8;
        const float4* p = (const float4*)(src + idx);
        float4 f0 = p[0], f1 = p[1];
        uint4 u;
        u.x = (unsigned)bf16_bits(f0.x) | ((unsigned)bf16_bits(f0.y) << 16);
        u.y = (unsigned)bf16_bits(f0.z) | ((unsigned)bf16_bits(f0.w) << 16);
        u.z = (unsigned)bf16_bits(f1.x) | ((unsigned)bf16_bits(f1.y) << 16);
        u.w = (unsigned)bf16_bits(f1.z) | ((unsigned)bf16_bits(f1.w) << 16);
        *(uint4*)(w16 + (size_t)which * 147456 + idx) = u;
        return;
    }
    const int xi = bx - 288;
    const int n0 = (xi & 7) * 128;
    const int t = xi >> 3;               // 0..95
    const int c0 = (t % 12) * 32;
    const int b = t / 12;
    {
        int c = tid >> 3, nq = (tid & 7) * 16;
        const float* sp = x1 + ((size_t)b*C + c0 + c)*N + n0 + nq;
        #pragma unroll
        for (int i = 0; i < 4; ++i)
            *(float4*)&tile[c][nq + 4*i] = *(const float4*)(sp + 4*i);
    }
    __syncthreads();
    {
        int n = tid >> 1, cb = (tid & 1) * 16;
        unsigned short* dp = x1T + ((size_t)b*N + n0 + n)*C + c0 + cb;
        #pragma unroll
        for (int half = 0; half < 2; ++half) {
            bf16x8 v;
            #pragma unroll
            for (int j = 0; j < 8; ++j)
                v[j] = (short)bf16_bits(tile[cb + half*8 + j][n]);
            *(bf16x8*)(dp + half*8) = v;
        }
    }
}

// ---------------------------------------------------------------------------
// MFMA projection: acc[n][o] = sum_c XT[n][c] * Wb[o][c]
// MODE 2: out fp32 spatial [b][384][1024] + bias + residual
// MODE 3: out bf16 token-major [b][1024][384] + bias  AND fp32 spatial + bias
// grid (16 n-tiles, 6 o-tiles, 8 b), 256 threads
// ---------------------------------------------------------------------------
template<int MODE>
__global__ __launch_bounds__(256) void proj_mfma(const unsigned short* __restrict__ XT,
                                                 const unsigned short* __restrict__ Wb,
                                                 const float* __restrict__ bias,
                                                 const float* __restrict__ res,
                                                 void* __restrict__ out,
                                                 float* __restrict__ out2)
{
    __shared__ __align__(16) char smem[64*72*2*2];   // 18,432 B
    unsigned short* sA = (unsigned short*)smem;      // [64n][72c]
    unsigned short* sB = sA + 64*72;                 // [64o][72c]
    float* ep = (float*)smem;                        // epilogue [64n][65o]

    const int tid = threadIdx.x;
    const int lane = tid & 63, w = tid >> 6;
    const int l15 = lane & 15, lq = lane >> 4;
    const int n0 = blockIdx.x * 64, o0 = blockIdx.y * 64, b = blockIdx.z;
    const int qn = (w & 1) * 32, qo = (w >> 1) * 32;

    const unsigned short* xg = XT + ((size_t)b*N + n0)*C;
    const unsigned short* wg = Wb + (size_t)o0*C;

    const f32x4 zero = {0.f, 0.f, 0.f, 0.f};
    f32x4 a00 = zero, a01 = zero, a10 = zero, a11 = zero;

    const int r = tid >> 2, c8 = (tid & 3) * 8;
    for (int c0 = 0; c0 < C; c0 += 64) {
        __syncthreads();
        *(bf16x8*)(sA + r*72 + c8)      = *(const bf16x8*)(xg + (size_t)r*C + c0 + c8);
        *(bf16x8*)(sA + r*72 + c8 + 32) = *(const bf16x8*)(xg + (size_t)r*C + c0 + c8 + 32);
        *(bf16x8*)(sB + r*72 + c8)      = *(const bf16x8*)(wg + (size_t)r*C + c0 + c8);
        *(bf16x8*)(sB + r*72 + c8 + 32) = *(const bf16x8*)(wg + (size_t)r*C + c0 + c8 + 32);
        __syncthreads();
        #pragma unroll
        for (int ks = 0; ks < 2; ++ks) {
            bf16x8 fa0 = *(const bf16x8*)(sA + (qn + l15)*72      + ks*32 + lq*8);
            bf16x8 fa1 = *(const bf16x8*)(sA + (qn + 16 + l15)*72 + ks*32 + lq*8);
            bf16x8 fb0 = *(const bf16x8*)(sB + (qo + l15)*72      + ks*32 + lq*8);
            bf16x8 fb1 = *(const bf16x8*)(sB + (qo + 16 + l15)*72 + ks*32 + lq*8);
            a00 = __builtin_amdgcn_mfma_f32_16x16x32_bf16(fa0, fb0, a00, 0, 0, 0);
            a01 = __builtin_amdgcn_mfma_f32_16x16x32_bf16(fa0, fb1, a01, 0, 0, 0);
            a10 = __builtin_amdgcn_mfma_f32_16x16x32_bf16(fa1, fb0, a10, 0, 0, 0);
            a11 = __builtin_amdgcn_mfma_f32_16x16x32_bf16(fa1, fb1, a11, 0, 0, 0);
        }
    }
    __syncthreads();
    #pragma unroll
    for (int rr = 0; rr < 4; ++rr) {
        int nr0 = qn + 4*lq + rr, nr1 = qn + 16 + 4*lq + rr;
        ep[nr0*65 + qo + l15]      = a00[rr];
        ep[nr0*65 + qo + 16 + l15] = a01[rr];
        ep[nr1*65 + qo + l15]      = a10[rr];
        ep[nr1*65 + qo + 16 + l15] = a11[rr];
    }
    __syncthreads();

    if constexpr (MODE == 3) {
        {   // token-major bf16
            int n = tid >> 2, ch = tid & 3;
            unsigned short* op = (unsigned short*)out + ((size_t)b*N + n0 + n)*C + o0;
            #pragma unroll
            for (int half = 0; half < 2; ++half) {
                int ob = ch*8 + half*32;
                bf16x8 v;
                #pragma unroll
                for (int j = 0; j < 8; ++j)
                    v[j] = (short)bf16_bits(ep[n*65 + ob + j] + bias[o0 + ob + j]);
                *(bf16x8*)(op + ob) = v;
            }
        }
        {   // fp32 spatial
            int o = tid >> 2, nc = (tid & 3) * 16;
            float bz = bias[o0 + o];
            float* dp = out2 + ((size_t)b*C + o0 + o)*N + n0 + nc;
            #pragma unroll
            for (int i = 0; i < 4; ++i) {
                float4 v;
                v.x = ep[(nc + 4*i + 0)*65 + o] + bz;
                v.y = ep[(nc + 4*i + 1)*65 + o] + bz;
                v.z = ep[(nc + 4*i + 2)*65 + o] + bz;
                v.w = ep[(nc + 4*i + 3)*65 + o] + bz;
                *(float4*)(dp + 4*i) = v;
            }
        }
    } else {
        int o = tid >> 2, nc = (tid & 3) * 16;
        float bz = bias[o0 + o];
        size_t base = ((size_t)b*C + o0 + o)*N + n0 + nc;
        #pragma unroll
        for (int i = 0; i < 4; ++i) {
            float4 rv = *(const float4*)(res + base + 4*i);
            float4 v;
            v.x = ep[(nc + 4*i + 0)*65 + o] + bz + rv.x;
            v.y = ep[(nc + 4*i + 1)*65 + o] + bz + rv.y;
            v.z = ep[(nc + 4*i + 2)*65 + o] + bz + rv.z;
            v.w = ep[(nc + 4*i + 3)*65 + o] + bz + rv.w;
            *(float4*)((float*)out + base + 4*i) = v;
        }
    }
}

// ---------------------------------------------------------------------------
// Fused K+V projection: one staging of sampT, two weight sets, two outputs.
// K16: bf16 token-major [b][1024][384], scaled by SCALE.
// V16: bf16 spatial [b][384][1024].
// grid (16 n-tiles, 6 o-tiles, 8 b)
// ---------------------------------------------------------------------------
__global__ __launch_bounds__(256) void proj_kv(const unsigned short* __restrict__ XT,
                                               const unsigned short* __restrict__ Wk,
                                               const float* __restrict__ bk,
                                               const unsigned short* __restrict__ Wv,
                                               const float* __restrict__ bv,
                                               unsigned short* __restrict__ K16,
                                               unsigned short* __restrict__ V16)
{
    __shared__ __align__(16) char smem[64*72*2*3];   // 27,648 B
    unsigned short* sA  = (unsigned short*)smem;
    unsigned short* sBk = sA + 64*72;
    unsigned short* sBv = sA + 2*64*72;
    float* ep = (float*)smem;                        // [64n][65o] = 16,640 B

    const int tid = threadIdx.x;
    const int lane = tid & 63, w = tid >> 6;
    const int l15 = lane & 15, lq = lane >> 4;
    const int n0 = blockIdx.x * 64, o0 = blockIdx.y * 64, b = blockIdx.z;
    const int qn = (w & 1) * 32, qo = (w >> 1) * 32;

    const unsigned short* xg = XT + ((size_t)b*N + n0)*C;
    const unsigned short* wkg = Wk + (size_t)o0*C;
    const unsigned short* wvg = Wv + (size_t)o0*C;

    const f32x4 zero = {0.f, 0.f, 0.f, 0.f};
    f32x4 k00 = zero, k01 = zero, k10 = zero, k11 = zero;
    f32x4 v00 = zero, v01 = zero, v10 = zero, v11 = zero;

    const int r = tid >> 2, c8 = (tid & 3) * 8;
    for (int c0 = 0; c0 < C; c0 += 64) {
        __syncthreads();
        *(bf16x8*)(sA  + r*72 + c8)      = *(const bf16x8*)(xg  + (size_t)r*C + c0 + c8);
        *(bf16x8*)(sA  + r*72 + c8 + 32) = *(const bf16x8*)(xg  + (size_t)r*C + c0 + c8 + 32);
        *(bf16x8*)(sBk + r*72 + c8)      = *(const bf16x8*)(wkg + (size_t)r*C + c0 + c8);
        *(bf16x8*)(sBk + r*72 + c8 + 32) = *(const bf16x8*)(wkg + (size_t)r*C + c0 + c8 + 32);
        *(bf16x8*)(sBv + r*72 + c8)      = *(const bf16x8*)(wvg + (size_t)r*C + c0 + c8);
        *(bf16x8*)(sBv + r*72 + c8 + 32) = *(const bf16x8*)(wvg + (size_t)r*C + c0 + c8 + 32);
        __syncthreads();
        #pragma unroll
        for (int ks = 0; ks < 2; ++ks) {
            bf16x8 fa0 = *(const bf16x8*)(sA + (qn + l15)*72      + ks*32 + lq*8);
            bf16x8 fa1 = *(const bf16x8*)(sA + (qn + 16 + l15)*72 + ks*32 + lq*8);
            bf16x8 fk0 = *(const bf16x8*)(sBk + (qo + l15)*72      + ks*32 + lq*8);
            bf16x8 fk1 = *(const bf16x8*)(sBk + (qo + 16 + l15)*72 + ks*32 + lq*8);
            bf16x8 fv0 = *(const bf16x8*)(sBv + (qo + l15)*72      + ks*32 + lq*8);
            bf16x8 fv1 = *(const bf16x8*)(sBv + (qo + 16 + l15)*72 + ks*32 + lq*8);
            k00 = __builtin_amdgcn_mfma_f32_16x16x32_bf16(fa0, fk0, k00, 0, 0, 0);
            k01 = __builtin_amdgcn_mfma_f32_16x16x32_bf16(fa0, fk1, k01, 0, 0, 0);
            k10 = __builtin_amdgcn_mfma_f32_16x16x32_bf16(fa1, fk0, k10, 0, 0, 0);
            k11 = __builtin_amdgcn_mfma_f32_16x16x32_bf16(fa1, fk1, k11, 0, 0, 0);
            v00 = __builtin_amdgcn_mfma_f32_16x16x32_bf16(fa0, fv0, v00, 0, 0, 0);
            v01 = __builtin_amdgcn_mfma_f32_16x16x32_bf16(fa0, fv1, v01, 0, 0, 0);
            v10 = __builtin_amdgcn_mfma_f32_16x16x32_bf16(fa1, fv0, v10, 0, 0, 0);
            v11 = __builtin_amdgcn_mfma_f32_16x16x32_bf16(fa1, fv1, v11, 0, 0, 0);
        }
    }
    // ---- K epilogue (token-major bf16, *SCALE) ----
    __syncthreads();
    #pragma unroll
    for (int rr = 0; rr < 4; ++rr) {
        int nr0 = qn + 4*lq + rr, nr1 = qn + 16 + 4*lq + rr;
        ep[nr0*65 + qo + l15]      = k00[rr];
        ep[nr0*65 + qo + 16 + l15] = k01[rr];
        ep[nr1*65 + qo + l15]      = k10[rr];
        ep[nr1*65 + qo + 16 + l15] = k11[rr];
    }
    __syncthreads();
    {
        int n = tid >> 2, ch = tid & 3;
        unsigned short* op = K16 + ((size_t)b*N + n0 + n)*C + o0;
        #pragma unroll
        for (int half = 0; half < 2; ++half) {
            int ob = ch*8 + half*32;
            bf16x8 v;
            #pragma unroll
            for (int j = 0; j < 8; ++j)
                v[j] = (short)bf16_bits((ep[n*65 + ob + j] + bk[o0 + ob + j]) * SCALE);
            *(bf16x8*)(op + ob) = v;
        }
    }
    // ---- V epilogue (spatial bf16) ----
    __syncthreads();
    #pragma unroll
    for (int rr = 0; rr < 4; ++rr) {
        int nr0 = qn + 4*lq + rr, nr1 = qn + 16 + 4*lq + rr;
        ep[nr0*65 + qo + l15]      = v00[rr];
        ep[nr0*65 + qo + 16 + l15] = v01[rr];
        ep[nr1*65 + qo + l15]      = v10[rr];
        ep[nr1*65 + qo + 16 + l15] = v11[rr];
    }
    __syncthreads();
    {
        int o = tid >> 2, nc = (tid & 3) * 16;
        float bz = bv[o0 + o];
        unsigned short* op = V16 + ((size_t)b*C + o0 + o)*N + n0 + nc;
        #pragma unroll
        for (int half = 0; half < 2; ++half) {
            bf16x8 v;
            #pragma unroll
            for (int j = 0; j < 8; ++j)
                v[j] = (short)bf16_bits(ep[(nc + half*8 + j)*65 + o] + bz);
            *(bf16x8*)(op + half*8) = v;
        }
    }
}

// ---------------------------------------------------------------------------
// Fused offset path: depthwise 5x5 conv + GELU + pointwise(2) + tanh + grid
// + bilinear gather -> token-major bf16 sampT. grid (16 n-chunks of 64, 24 bg)
// ---------------------------------------------------------------------------
__global__ __launch_bounds__(256) void dwoff_bilin(const float* __restrict__ qspat,
                                                   const float* __restrict__ wdw,
                                                   const float* __restrict__ bdw,
                                                   const float* __restrict__ wpw,
                                                   const float* __restrict__ bpw,
                                                   const float* __restrict__ x2,
                                                   unsigned short* __restrict__ sampT)
{
    __shared__ float r0[4][64], r1[4][64];
    __shared__ float4 cbuf[64];
    __shared__ unsigned short st[64][130];
    const int tid = threadIdx.x;
    const int n0 = blockIdx.x * 64, bg = blockIdx.y;
    const int nl = tid & 63, cq = tid >> 6;
    const int n = n0 + nl, y = n >> 5, x = n & 31;
    const float* qb = qspat + (size_t)bg*Cg*N;

    float a0 = 0.f, a1 = 0.f;
    for (int i = 0; i < 32; ++i) {
        int c = cq*32 + i;
        const float* qc = qb + (size_t)c*N;
        const float* wc = wdw + c*25;
        float acc = bdw[c];
        #pragma unroll
        for (int ky = 0; ky < 5; ++ky) {
            int yy = y + ky - 2;
            if (yy < 0 || yy >= H) continue;
            #pragma unroll
            for (int kx = 0; kx < 5; ++kx) {
                int xx = x + kx - 2;
                if (xx < 0 || xx >= W) continue;
                acc += wc[ky*5 + kx] * qc[yy*W + xx];
            }
        }
        float g = 0.5f*acc*(1.0f + tanhf(0.7978845608028654f*(acc + 0.044715f*acc*acc*acc)));
        a0 += wpw[c] * g;
        a1 += wpw[Cg + c] * g;
    }
    r0[cq][nl] = a0; r1[cq][nl] = a1;
    __syncthreads();
    if (tid < 64) {
        a0 = bpw[0] + r0[0][nl] + r0[1][nl] + r0[2][nl] + r0[3][nl];
        a1 = bpw[1] + r1[0][nl] + r1[1][nl] + r1[2][nl] + r1[3][nl];
        float dx = tanhf(a0) * (2.0f / W);
        float dy = tanhf(a1) * (2.0f / H);
        float rx = (x + 0.5f) / W * 2.0f - 1.0f;
        float ry = (y + 0.5f) / H * 2.0f - 1.0f;
        float px = fminf(fmaxf(rx + dx, -1.0f), 1.0f);
        float py = fminf(fmaxf(ry + dy, -1.0f), 1.0f);
        float gx = (px + 1.0f) * 0.5f * (W - 1);
        float gy = (py + 1.0f) * 0.5f * (H - 1);
        float x0 = floorf(gx), y0 = floorf(gy);
        float wx1 = gx - x0, wy1 = gy - y0;
        x0 = fminf(fmaxf(x0, 0.0f), (float)(W - 1));
        y0 = fminf(fmaxf(y0, 0.0f), (float)(H - 1));
        cbuf[nl] = make_float4(x0, y0, wx1, wy1);
    }
    __syncthreads();
    float4 c4 = cbuf[nl];
    int x0 = (int)c4.x, y0 = (int)c4.y;
    float wx1 = c4.z, wy1 = c4.w;
    int x1 = min(x0 + 1, W - 1), y1 = min(y0 + 1, H - 1);
    float wx0 = 1.0f - wx1, wy0 = 1.0f - wy1;
    const float* base = x2 + (size_t)bg*Cg*N;
    #pragma unroll 4
    for (int i = 0; i < 32; ++i) {
        int c = cq*32 + i;
        const float* img = base + (size_t)c*N;
        float v00 = img[y0*W + x0], v01 = img[y0*W + x1];
        float v10 = img[y1*W + x0], v11 = img[y1*W + x1];
        float v = wy0*(wx0*v00 + wx1*v01) + wy1*(wx0*v10 + wx1*v11);
        st[nl][c] = bf16_bits(v);
    }
    __syncthreads();
    {
        int b = bg / 3, g = bg % 3;
        int nn = tid >> 2;
        unsigned short* dp = sampT + ((size_t)b*N + n0 + nn)*C + g*Cg;
        #pragma unroll
        for (int i = 0; i < 4; ++i) {
            int c8 = ((tid & 3) + 4*i) * 8;
            *(bf16x8*)(dp + c8) = *(const bf16x8*)&st[nn][c8];
        }
    }
}

// ---------------------------------------------------------------------------
// Fused attention: QK^T (MFMA) + 2-pass no-max softmax + attn write + PV.
// LDS 46.6KB -> 3 blocks/CU. grid (16, 96)
// ---------------------------------------------------------------------------
__global__ __launch_bounds__(256) void attn_fused(const unsigned short* __restrict__ Q16,
                                                  const unsigned short* __restrict__ K16,
                                                  const unsigned short* __restrict__ V16,
                                                  float* __restrict__ attn,
                                                  unsigned short* __restrict__ OT)
{
    __shared__ __align__(16) unsigned short ks[256*40];    // 20,480 B
    __shared__ __align__(16) unsigned short vs[32*264];    // 16,896 B
    __shared__ __align__(16) unsigned short ps[4][16*72];  //  9,216 B

    const int tid = threadIdx.x;
    const int lane = tid & 63, w = tid >> 6;
    const int l15 = lane & 15, lq = lane >> 4;
    const int nb = blockIdx.x, bh = blockIdx.y;
    const int b = bh / HEADS, h = bh - b*HEADS;

    const unsigned short* qg = Q16 + ((size_t)b*N + nb*64)*C + h*32;
    const unsigned short* kg = K16 + (size_t)b*N*C + h*32;
    const unsigned short* vg = V16 + ((size_t)b*C + h*32)*N;

    // Q fragment straight from global (one-time, L2-resident)
    const bf16x8 afrag = *(const bf16x8*)(qg + (size_t)(w*16 + l15)*C + lq*8);

    float sm[4] = {0.f, 0.f, 0.f, 0.f};
    f32x4 s[16];
    const f32x4 zero = {0.f, 0.f, 0.f, 0.f};

    // ------------------ PASS 1: row sums (no max needed; |s| small) --------
    for (int ch = 0; ch < 4; ++ch) {
        __syncthreads();
        #pragma unroll
        for (int i = 0; i < 4; ++i) {
            int m = i*64 + (tid >> 2), c8 = (tid & 3) * 8;
            *(bf16x8*)(ks + m*40 + c8) = *(const bf16x8*)(kg + ((size_t)ch*256 + m)*C + c8);
        }
        __syncthreads();
        #pragma unroll
        for (int t = 0; t < 16; ++t) {
            bf16x8 bfrag = *(const bf16x8*)(ks + (16*t + l15)*40 + lq*8);
            s[t] = __builtin_amdgcn_mfma_f32_16x16x32_bf16(afrag, bfrag, zero, 0, 0, 0);
        }
        #pragma unroll
        for (int r = 0; r < 4; ++r) {
            float es = 0.f;
            #pragma unroll
            for (int t = 0; t < 16; ++t) es += __expf(s[t][r]);
            es += __shfl_xor(es, 1);
            es += __shfl_xor(es, 2);
            es += __shfl_xor(es, 4);
            es += __shfl_xor(es, 8);
            sm[r] += es;
        }
    }
    float lns[4];
    #pragma unroll
    for (int r = 0; r < 4; ++r) lns[r] = __logf(sm[r]);

    // ------------------ PASS 2: P write + PV ------------------
    f32x4 outf[2] = {zero, zero};
    unsigned short* pw = ps[w];
    float* arow = attn + ((size_t)bh*N + (size_t)nb*64 + w*16)*N;

    for (int ch = 0; ch < 4; ++ch) {
        __syncthreads();
        #pragma unroll
        for (int i = 0; i < 4; ++i) {
            int m = i*64 + (tid >> 2), c8 = (tid & 3) * 8;
            *(bf16x8*)(ks + m*40 + c8) = *(const bf16x8*)(kg + ((size_t)ch*256 + m)*C + c8);
        }
        #pragma unroll
        for (int i = 0; i < 4; ++i) {
            int u = tid + i*256;
            int cl = u >> 5, gg = u & 31;
            *(bf16x8*)(vs + cl*264 + gg*8) = *(const bf16x8*)(vg + (size_t)cl*N + ch*256 + gg*8);
        }
        __syncthreads();
        #pragma unroll
        for (int t = 0; t < 16; ++t) {
            bf16x8 bfrag = *(const bf16x8*)(ks + (16*t + l15)*40 + lq*8);
            s[t] = __builtin_amdgcn_mfma_f32_16x16x32_bf16(afrag, bfrag, zero, 0, 0, 0);
        }
        // 64-col quarters: softmax-write then PV
        #pragma unroll
        for (int qr = 0; qr < 4; ++qr) {
            #pragma unroll
            for (int r = 0; r < 4; ++r) {
                int n_loc = 4*lq + r;
                float* ar = arow + (size_t)n_loc*N + ch*256 + qr*64;
                #pragma unroll
                for (int tt = 0; tt < 4; ++tt) {
                    float p = __expf(s[qr*4 + tt][r] - lns[r]);
                    int m_loc = 16*tt + l15;
                    ar[m_loc] = p;
                    pw[n_loc*72 + m_loc] = bf16_bits(p);
                }
            }
            __asm volatile("" ::: "memory");
            #pragma unroll
            for (int kk = 0; kk < 2; ++kk) {
                bf16x8 pa = *(const bf16x8*)(pw + l15*72 + kk*32 + lq*8);
                #pragma unroll
                for (int ct = 0; ct < 2; ++ct) {
                    bf16x8 vb = *(const bf16x8*)(vs + (16*ct + l15)*264 + qr*64 + kk*32 + lq*8);
                    outf[ct] = __builtin_amdgcn_mfma_f32_16x16x32_bf16(pa, vb, outf[ct], 0, 0, 0);
                }
            }
            __asm volatile("" ::: "memory");
        }
    }

    // write PV tile token-major bf16 via per-wave LDS repack
    float* sc = (float*)pw;   // [16n][33c] f32 = 2112 B < 2304 B
    #pragma unroll
    for (int ct = 0; ct < 2; ++ct)
        #pragma unroll
        for (int r = 0; r < 4; ++r)
            sc[(4*lq + r)*33 + ct*16 + l15] = outf[ct][r];
    __asm volatile("" ::: "memory");
    {
        int n = lane >> 2, c8 = (lane & 3) * 8;
        bf16x8 v;
        #pragma unroll
        for (int j = 0; j < 8; ++j)
            v[j] = (short)bf16_bits(sc[n*33 + c8 + j]);
        *(bf16x8*)(OT + ((size_t)b*N + nb*64 + w*16 + n)*C + h*32 + c8) = v;
    }
}

// ---------------------------------------------------------------------------
extern "C" void kernel_launch(void* const* d_in, const int* in_sizes, int n_in,
                              void* d_out, int out_size, void* d_ws, size_t ws_size,
                              hipStream_t stream)
{
    const float* x1  = (const float*)d_in[0];
    const float* x2  = (const float*)d_in[1];
    const float* wq  = (const float*)d_in[2];
    const float* bq  = (const float*)d_in[3];
    const float* wdw = (const float*)d_in[4];
    const float* bdw = (const float*)d_in[5];
    const float* wpw = (const float*)d_in[6];
    const float* bpw = (const float*)d_in[7];
    const float* wk  = (const float*)d_in[8];
    const float* bk  = (const float*)d_in[9];
    const float* wv  = (const float*)d_in[10];
    const float* bv  = (const float*)d_in[11];
    const float* wo  = (const float*)d_in[12];
    const float* bo  = (const float*)d_in[13];

    const size_t P = (size_t)B * C * N;          // 3,145,728 floats
    float* ws = (float*)d_ws;
    unsigned short* Q16   = (unsigned short*)ws;             // 0.5P
    float*          qspat = ws + P/2;                        // 1P fp32
    unsigned short* sampT = (unsigned short*)(ws + 3*P/2);   // 0.5P
    unsigned short* K16   = (unsigned short*)(ws + 2*P);     // 0.5P
    unsigned short* V16   = (unsigned short*)(ws + 5*P/2);   // 0.5P
    unsigned short* x1T   = (unsigned short*)(ws + 3*P);     // 0.5P, reused as OT
    unsigned short* OT    = x1T;
    unsigned short* w16   = (unsigned short*)(ws + 7*P/2);   // 4*147456 halves
    unsigned short* w16q = w16;
    unsigned short* w16k = w16 + 147456;
    unsigned short* w16v = w16 + 2*147456;
    unsigned short* w16o = w16 + 3*147456;

    float* ybuf = (float*)d_out;                 // (B,C,H,W)
    float* attn = (float*)d_out + P;             // (B,HEADS,N,N)

    prep<<<dim3(1056), 256, 0, stream>>>(wq, wk, wv, wo, x1, w16, x1T);
    proj_mfma<3><<<dim3(16, 6, 8), 256, 0, stream>>>(x1T, w16q, bq, nullptr, Q16, qspat);
    dwoff_bilin<<<dim3(16, BG), 256, 0, stream>>>(qspat, wdw, bdw, wpw, bpw, x2, sampT);
    proj_kv<<<dim3(16, 6, 8), 256, 0, stream>>>(sampT, w16k, bk, w16v, bv, K16, V16);
    attn_fused<<<dim3(16, 96), 256, 0, stream>>>(Q16, K16, V16, attn, OT);
    proj_mfma<2><<<dim3(16, 6, 8), 256, 0, stream>>>(OT, w16o, bo, x1, ybuf, nullptr);
}

// Round 5
// 216.354 us; speedup vs baseline: 1.3215x; 1.3215x over previous
//
#include <hip/hip_runtime.h>
#include <hip/hip_bf16.h>

static constexpr int B = 8;
static constexpr int C = 384;
static constexpr int H = 32;
static constexpr int W = 32;
static constexpr int N = 1024;      // H*W
static constexpr int Cg = 128;      // C/G
static constexpr int HEADS = 12;
static constexpr int BG = 24;       // B*G
static constexpr float SCALE = 0.17677669529663687f; // hc^-0.5

typedef short bf16x8 __attribute__((ext_vector_type(8)));
typedef float f32x4 __attribute__((ext_vector_type(4)));

__device__ __forceinline__ unsigned short bf16_bits(float x) {
    __hip_bfloat16 h = __float2bfloat16(x);
    return __builtin_bit_cast(unsigned short, h);
}

// ---------------------------------------------------------------------------
// prep: blocks 0..287 convert 4 weight matrices to bf16; blocks 288..1055
// transpose x1 fp32 [b][384][1024] -> bf16 token-major [b][1024][384].
// ---------------------------------------------------------------------------
__global__ __launch_bounds__(256) void prep(const float* __restrict__ wq,
                                            const float* __restrict__ wk,
                                            const float* __restrict__ wv,
                                            const float* __restrict__ wo,
                                            const float* __restrict__ x1,
                                            unsigned short* __restrict__ w16,
                                            unsigned short* __restrict__ x1T)
{
    __shared__ float tile[32][132];
    const int bx = blockIdx.x;
    const int tid = threadIdx.x;
    if (bx < 288) {
        int which = bx / 72, blk = bx - which*72;
        const float* src = (which == 0) ? wq : (which == 1) ? wk : (which == 2) ? wv : wo;
        int idx = (blk*256 + tid) * 8;
        const float4* p = (const float4*)(src + idx);
        float4 f0 = p[0], f1 = p[1];
        uint4 u;
        u.x = (unsigned)bf16_bits(f0.x) | ((unsigned)bf16_bits(f0.y) << 16);
        u.y = (unsigned)bf16_bits(f0.z) | ((unsigned)bf16_bits(f0.w) << 16);
        u.z = (unsigned)bf16_bits(f1.x) | ((unsigned)bf16_bits(f1.y) << 16);
        u.w = (unsigned)bf16_bits(f1.z) | ((unsigned)bf16_bits(f1.w) << 16);
        *(uint4*)(w16 + (size_t)which * 147456 + idx) = u;
        return;
    }
    const int xi = bx - 288;
    const int n0 = (xi & 7) * 128;
    const int t = xi >> 3;               // 0..95
    const int c0 = (t % 12) * 32;
    const int b = t / 12;
    {
        int c = tid >> 3, nq = (tid & 7) * 16;
        const float* sp = x1 + ((size_t)b*C + c0 + c)*N + n0 + nq;
        #pragma unroll
        for (int i = 0; i < 4; ++i)
            *(float4*)&tile[c][nq + 4*i] = *(const float4*)(sp + 4*i);
    }
    __syncthreads();
    {
        int n = tid >> 1, cb = (tid & 1) * 16;
        unsigned short* dp = x1T + ((size_t)b*N + n0 + n)*C + c0 + cb;
        #pragma unroll
        for (int half = 0; half < 2; ++half) {
            bf16x8 v;
            #pragma unroll
            for (int j = 0; j < 8; ++j)
                v[j] = (short)bf16_bits(tile[cb + half*8 + j][n]);
            *(bf16x8*)(dp + half*8) = v;
        }
    }
}

// ---------------------------------------------------------------------------
// MFMA projection: acc[n][o] = sum_c XT[n][c] * Wb[o][c]
// MODE 2: out fp32 spatial + bias + residual
// MODE 3: out bf16 token-major + bias  AND fp32 spatial + bias
// grid (16 n-tiles, 6 o-tiles, 8 b), 256 threads
// ---------------------------------------------------------------------------
template<int MODE>
__global__ __launch_bounds__(256) void proj_mfma(const unsigned short* __restrict__ XT,
                                                 const unsigned short* __restrict__ Wb,
                                                 const float* __restrict__ bias,
                                                 const float* __restrict__ res,
                                                 void* __restrict__ out,
                                                 float* __restrict__ out2)
{
    __shared__ __align__(16) char smem[64*72*2*2];   // 18,432 B
    unsigned short* sA = (unsigned short*)smem;      // [64n][72c]
    unsigned short* sB = sA + 64*72;                 // [64o][72c]
    float* ep = (float*)smem;                        // epilogue [64n][65o]

    const int tid = threadIdx.x;
    const int lane = tid & 63, w = tid >> 6;
    const int l15 = lane & 15, lq = lane >> 4;
    const int n0 = blockIdx.x * 64, o0 = blockIdx.y * 64, b = blockIdx.z;
    const int qn = (w & 1) * 32, qo = (w >> 1) * 32;

    const unsigned short* xg = XT + ((size_t)b*N + n0)*C;
    const unsigned short* wg = Wb + (size_t)o0*C;

    const f32x4 zero = {0.f, 0.f, 0.f, 0.f};
    f32x4 a00 = zero, a01 = zero, a10 = zero, a11 = zero;

    const int r = tid >> 2, c8 = (tid & 3) * 8;
    for (int c0 = 0; c0 < C; c0 += 64) {
        __syncthreads();
        *(bf16x8*)(sA + r*72 + c8)      = *(const bf16x8*)(xg + (size_t)r*C + c0 + c8);
        *(bf16x8*)(sA + r*72 + c8 + 32) = *(const bf16x8*)(xg + (size_t)r*C + c0 + c8 + 32);
        *(bf16x8*)(sB + r*72 + c8)      = *(const bf16x8*)(wg + (size_t)r*C + c0 + c8);
        *(bf16x8*)(sB + r*72 + c8 + 32) = *(const bf16x8*)(wg + (size_t)r*C + c0 + c8 + 32);
        __syncthreads();
        #pragma unroll
        for (int ks = 0; ks < 2; ++ks) {
            bf16x8 fa0 = *(const bf16x8*)(sA + (qn + l15)*72      + ks*32 + lq*8);
            bf16x8 fa1 = *(const bf16x8*)(sA + (qn + 16 + l15)*72 + ks*32 + lq*8);
            bf16x8 fb0 = *(const bf16x8*)(sB + (qo + l15)*72      + ks*32 + lq*8);
            bf16x8 fb1 = *(const bf16x8*)(sB + (qo + 16 + l15)*72 + ks*32 + lq*8);
            a00 = __builtin_amdgcn_mfma_f32_16x16x32_bf16(fa0, fb0, a00, 0, 0, 0);
            a01 = __builtin_amdgcn_mfma_f32_16x16x32_bf16(fa0, fb1, a01, 0, 0, 0);
            a10 = __builtin_amdgcn_mfma_f32_16x16x32_bf16(fa1, fb0, a10, 0, 0, 0);
            a11 = __builtin_amdgcn_mfma_f32_16x16x32_bf16(fa1, fb1, a11, 0, 0, 0);
        }
    }
    __syncthreads();
    #pragma unroll
    for (int rr = 0; rr < 4; ++rr) {
        int nr0 = qn + 4*lq + rr, nr1 = qn + 16 + 4*lq + rr;
        ep[nr0*65 + qo + l15]      = a00[rr];
        ep[nr0*65 + qo + 16 + l15] = a01[rr];
        ep[nr1*65 + qo + l15]      = a10[rr];
        ep[nr1*65 + qo + 16 + l15] = a11[rr];
    }
    __syncthreads();

    if constexpr (MODE == 3) {
        {   // token-major bf16
            int n = tid >> 2, ch = tid & 3;
            unsigned short* op = (unsigned short*)out + ((size_t)b*N + n0 + n)*C + o0;
            #pragma unroll
            for (int half = 0; half < 2; ++half) {
                int ob = ch*8 + half*32;
                bf16x8 v;
                #pragma unroll
                for (int j = 0; j < 8; ++j)
                    v[j] = (short)bf16_bits(ep[n*65 + ob + j] + bias[o0 + ob + j]);
                *(bf16x8*)(op + ob) = v;
            }
        }
        {   // fp32 spatial
            int o = tid >> 2, nc = (tid & 3) * 16;
            float bz = bias[o0 + o];
            float* dp = out2 + ((size_t)b*C + o0 + o)*N + n0 + nc;
            #pragma unroll
            for (int i = 0; i < 4; ++i) {
                float4 v;
                v.x = ep[(nc + 4*i + 0)*65 + o] + bz;
                v.y = ep[(nc + 4*i + 1)*65 + o] + bz;
                v.z = ep[(nc + 4*i + 2)*65 + o] + bz;
                v.w = ep[(nc + 4*i + 3)*65 + o] + bz;
                *(float4*)(dp + 4*i) = v;
            }
        }
    } else {
        int o = tid >> 2, nc = (tid & 3) * 16;
        float bz = bias[o0 + o];
        size_t base = ((size_t)b*C + o0 + o)*N + n0 + nc;
        #pragma unroll
        for (int i = 0; i < 4; ++i) {
            float4 rv = *(const float4*)(res + base + 4*i);
            float4 v;
            v.x = ep[(nc + 4*i + 0)*65 + o] + bz + rv.x;
            v.y = ep[(nc + 4*i + 1)*65 + o] + bz + rv.y;
            v.z = ep[(nc + 4*i + 2)*65 + o] + bz + rv.z;
            v.w = ep[(nc + 4*i + 3)*65 + o] + bz + rv.w;
            *(float4*)((float*)out + base + 4*i) = v;
        }
    }
}

// ---------------------------------------------------------------------------
// Fused K+V projection: one staging of sampT, two weight sets, two outputs.
// ---------------------------------------------------------------------------
__global__ __launch_bounds__(256) void proj_kv(const unsigned short* __restrict__ XT,
                                               const unsigned short* __restrict__ Wk,
                                               const float* __restrict__ bk,
                                               const unsigned short* __restrict__ Wv,
                                               const float* __restrict__ bv,
                                               unsigned short* __restrict__ K16,
                                               unsigned short* __restrict__ V16)
{
    __shared__ __align__(16) char smem[64*72*2*3];   // 27,648 B
    unsigned short* sA  = (unsigned short*)smem;
    unsigned short* sBk = sA + 64*72;
    unsigned short* sBv = sA + 2*64*72;
    float* ep = (float*)smem;                        // [64n][65o]

    const int tid = threadIdx.x;
    const int lane = tid & 63, w = tid >> 6;
    const int l15 = lane & 15, lq = lane >> 4;
    const int n0 = blockIdx.x * 64, o0 = blockIdx.y * 64, b = blockIdx.z;
    const int qn = (w & 1) * 32, qo = (w >> 1) * 32;

    const unsigned short* xg = XT + ((size_t)b*N + n0)*C;
    const unsigned short* wkg = Wk + (size_t)o0*C;
    const unsigned short* wvg = Wv + (size_t)o0*C;

    const f32x4 zero = {0.f, 0.f, 0.f, 0.f};
    f32x4 k00 = zero, k01 = zero, k10 = zero, k11 = zero;
    f32x4 v00 = zero, v01 = zero, v10 = zero, v11 = zero;

    const int r = tid >> 2, c8 = (tid & 3) * 8;
    for (int c0 = 0; c0 < C; c0 += 64) {
        __syncthreads();
        *(bf16x8*)(sA  + r*72 + c8)      = *(const bf16x8*)(xg  + (size_t)r*C + c0 + c8);
        *(bf16x8*)(sA  + r*72 + c8 + 32) = *(const bf16x8*)(xg  + (size_t)r*C + c0 + c8 + 32);
        *(bf16x8*)(sBk + r*72 + c8)      = *(const bf16x8*)(wkg + (size_t)r*C + c0 + c8);
        *(bf16x8*)(sBk + r*72 + c8 + 32) = *(const bf16x8*)(wkg + (size_t)r*C + c0 + c8 + 32);
        *(bf16x8*)(sBv + r*72 + c8)      = *(const bf16x8*)(wvg + (size_t)r*C + c0 + c8);
        *(bf16x8*)(sBv + r*72 + c8 + 32) = *(const bf16x8*)(wvg + (size_t)r*C + c0 + c8 + 32);
        __syncthreads();
        #pragma unroll
        for (int ks = 0; ks < 2; ++ks) {
            bf16x8 fa0 = *(const bf16x8*)(sA + (qn + l15)*72      + ks*32 + lq*8);
            bf16x8 fa1 = *(const bf16x8*)(sA + (qn + 16 + l15)*72 + ks*32 + lq*8);
            bf16x8 fk0 = *(const bf16x8*)(sBk + (qo + l15)*72      + ks*32 + lq*8);
            bf16x8 fk1 = *(const bf16x8*)(sBk + (qo + 16 + l15)*72 + ks*32 + lq*8);
            bf16x8 fv0 = *(const bf16x8*)(sBv + (qo + l15)*72      + ks*32 + lq*8);
            bf16x8 fv1 = *(const bf16x8*)(sBv + (qo + 16 + l15)*72 + ks*32 + lq*8);
            k00 = __builtin_amdgcn_mfma_f32_16x16x32_bf16(fa0, fk0, k00, 0, 0, 0);
            k01 = __builtin_amdgcn_mfma_f32_16x16x32_bf16(fa0, fk1, k01, 0, 0, 0);
            k10 = __builtin_amdgcn_mfma_f32_16x16x32_bf16(fa1, fk0, k10, 0, 0, 0);
            k11 = __builtin_amdgcn_mfma_f32_16x16x32_bf16(fa1, fk1, k11, 0, 0, 0);
            v00 = __builtin_amdgcn_mfma_f32_16x16x32_bf16(fa0, fv0, v00, 0, 0, 0);
            v01 = __builtin_amdgcn_mfma_f32_16x16x32_bf16(fa0, fv1, v01, 0, 0, 0);
            v10 = __builtin_amdgcn_mfma_f32_16x16x32_bf16(fa1, fv0, v10, 0, 0, 0);
            v11 = __builtin_amdgcn_mfma_f32_16x16x32_bf16(fa1, fv1, v11, 0, 0, 0);
        }
    }
    // ---- K epilogue (token-major bf16, *SCALE) ----
    __syncthreads();
    #pragma unroll
    for (int rr = 0; rr < 4; ++rr) {
        int nr0 = qn + 4*lq + rr, nr1 = qn + 16 + 4*lq + rr;
        ep[nr0*65 + qo + l15]      = k00[rr];
        ep[nr0*65 + qo + 16 + l15] = k01[rr];
        ep[nr1*65 + qo + l15]      = k10[rr];
        ep[nr1*65 + qo + 16 + l15] = k11[rr];
    }
    __syncthreads();
    {
        int n = tid >> 2, ch = tid & 3;
        unsigned short* op = K16 + ((size_t)b*N + n0 + n)*C + o0;
        #pragma unroll
        for (int half = 0; half < 2; ++half) {
            int ob = ch*8 + half*32;
            bf16x8 v;
            #pragma unroll
            for (int j = 0; j < 8; ++j)
                v[j] = (short)bf16_bits((ep[n*65 + ob + j] + bk[o0 + ob + j]) * SCALE);
            *(bf16x8*)(op + ob) = v;
        }
    }
    // ---- V epilogue (spatial bf16) ----
    __syncthreads();
    #pragma unroll
    for (int rr = 0; rr < 4; ++rr) {
        int nr0 = qn + 4*lq + rr, nr1 = qn + 16 + 4*lq + rr;
        ep[nr0*65 + qo + l15]      = v00[rr];
        ep[nr0*65 + qo + 16 + l15] = v01[rr];
        ep[nr1*65 + qo + l15]      = v10[rr];
        ep[nr1*65 + qo + 16 + l15] = v11[rr];
    }
    __syncthreads();
    {
        int o = tid >> 2, nc = (tid & 3) * 16;
        float bz = bv[o0 + o];
        unsigned short* op = V16 + ((size_t)b*C + o0 + o)*N + n0 + nc;
        #pragma unroll
        for (int half = 0; half < 2; ++half) {
            bf16x8 v;
            #pragma unroll
            for (int j = 0; j < 8; ++j)
                v[j] = (short)bf16_bits(ep[(nc + half*8 + j)*65 + o] + bz);
            *(bf16x8*)(op + half*8) = v;
        }
    }
}

// ---------------------------------------------------------------------------
// Depthwise 5x5 conv (SAME) + bias + tanh GELU. grid (4, 128, 24) — 12288
// blocks, 1 output/thread: occupancy-rich (was the R3-measured fast form).
// ---------------------------------------------------------------------------
__global__ __launch_bounds__(256) void dwconv_gelu(const float* __restrict__ q,
                                                   const float* __restrict__ wdw,
                                                   const float* __restrict__ bdw,
                                                   float* __restrict__ t)
{
    const int n = blockIdx.x * 256 + threadIdx.x;
    const int c = blockIdx.y, bg = blockIdx.z;
    const int y = n >> 5, x = n & 31;
    const float* qc = q + ((size_t)bg*Cg + c)*N;
    const float* wc = wdw + c*25;
    float acc = bdw[c];
    #pragma unroll
    for (int ky = 0; ky < 5; ++ky) {
        int yy = y + ky - 2;
        if (yy < 0 || yy >= H) continue;
        #pragma unroll
        for (int kx = 0; kx < 5; ++kx) {
            int xx = x + kx - 2;
            if (xx < 0 || xx >= W) continue;
            acc += wc[ky*5 + kx] * qc[yy*W + xx];
        }
    }
    float u = acc;
    float g = 0.5f*u*(1.0f + tanhf(0.7978845608028654f*(u + 0.044715f*u*u*u)));
    t[((size_t)bg*Cg + c)*N + n] = g;
}

// ---------------------------------------------------------------------------
// Pointwise conv (2 x Cg) + tanh -> clipped grid -> bilinear coords. grid(384)
// ---------------------------------------------------------------------------
__global__ __launch_bounds__(256) void offset_grid(const float* __restrict__ t,
                                                   const float* __restrict__ wpw,
                                                   const float* __restrict__ bpw,
                                                   float* __restrict__ coords)
{
    __shared__ float r0[4][64], r1[4][64];
    const int bx = blockIdx.x;
    const int bg = bx >> 4, n0 = (bx & 15) * 64;
    const int nl = threadIdx.x & 63, cq = threadIdx.x >> 6;
    const float* tb = t + ((size_t)bg*Cg + cq*32)*N + n0 + nl;
    float a0 = 0.f, a1 = 0.f;
    #pragma unroll 8
    for (int i = 0; i < 32; ++i) {
        float tv = tb[(size_t)i*N];
        a0 += wpw[cq*32 + i] * tv;
        a1 += wpw[Cg + cq*32 + i] * tv;
    }
    r0[cq][nl] = a0; r1[cq][nl] = a1;
    __syncthreads();
    if (threadIdx.x < 64) {
        int n = n0 + nl;
        a0 = bpw[0] + r0[0][nl] + r0[1][nl] + r0[2][nl] + r0[3][nl];
        a1 = bpw[1] + r1[0][nl] + r1[1][nl] + r1[2][nl] + r1[3][nl];
        const int x = n & 31, y = n >> 5;
        float dx = tanhf(a0) * (2.0f / W);
        float dy = tanhf(a1) * (2.0f / H);
        float rx = (x + 0.5f) / W * 2.0f - 1.0f;
        float ry = (y + 0.5f) / H * 2.0f - 1.0f;
        float px = fminf(fmaxf(rx + dx, -1.0f), 1.0f);
        float py = fminf(fmaxf(ry + dy, -1.0f), 1.0f);
        float gx = (px + 1.0f) * 0.5f * (W - 1);
        float gy = (py + 1.0f) * 0.5f * (H - 1);
        float x0 = floorf(gx), y0 = floorf(gy);
        float wx1 = gx - x0, wy1 = gy - y0;
        x0 = fminf(fmaxf(x0, 0.0f), (float)(W - 1));
        y0 = fminf(fmaxf(y0, 0.0f), (float)(H - 1));
        ((float4*)coords)[bg*N + n] = make_float4(x0, y0, wx1, wy1);
    }
}

// ---------------------------------------------------------------------------
// Bilinear gather of x2 -> token-major bf16 sampT. grid (16, 24)
// ---------------------------------------------------------------------------
__global__ __launch_bounds__(256) void bilin_sample(const float* __restrict__ x2,
                                                    const float* __restrict__ coords,
                                                    unsigned short* __restrict__ sampT)
{
    __shared__ unsigned short st[64][130];
    const int tid = threadIdx.x;
    const int n0 = blockIdx.x * 64, bg = blockIdx.y;
    const int b = bg / 3, g = bg % 3;
    const int nl = tid & 63, cq = tid >> 6;
    float4 c4 = ((const float4*)coords)[bg*N + n0 + nl];
    int x0 = (int)c4.x, y0 = (int)c4.y;
    float wx1 = c4.z, wy1 = c4.w;
    int x1 = min(x0 + 1, W - 1), y1 = min(y0 + 1, H - 1);
    float wx0 = 1.0f - wx1, wy0 = 1.0f - wy1;
    const float* base = x2 + (size_t)bg*Cg*N;
    #pragma unroll 4
    for (int i = 0; i < 32; ++i) {
        int c = cq*32 + i;
        const float* img = base + (size_t)c*N;
        float v00 = img[y0*W + x0], v01 = img[y0*W + x1];
        float v10 = img[y1*W + x0], v11 = img[y1*W + x1];
        float v = wy0*(wx0*v00 + wx1*v01) + wy1*(wx0*v10 + wx1*v11);
        st[nl][c] = bf16_bits(v);
    }
    __syncthreads();
    {
        int nn = tid >> 2;
        unsigned short* dp = sampT + ((size_t)b*N + n0 + nn)*C + g*Cg;
        #pragma unroll
        for (int i = 0; i < 4; ++i) {
            int c8 = ((tid & 3) + 4*i) * 8;
            *(bf16x8*)(dp + c8) = *(const bf16x8*)&st[nn][c8];
        }
    }
}

// ---------------------------------------------------------------------------
// Fused attention: QK^T (MFMA) + 2-pass no-max softmax + attn write + PV.
// LDS 46.6KB -> 3 blocks/CU. grid (16, 96)
// ---------------------------------------------------------------------------
__global__ __launch_bounds__(256) void attn_fused(const unsigned short* __restrict__ Q16,
                                                  const unsigned short* __restrict__ K16,
                                                  const unsigned short* __restrict__ V16,
                                                  float* __restrict__ attn,
                                                  unsigned short* __restrict__ OT)
{
    __shared__ __align__(16) unsigned short ks[256*40];    // 20,480 B
    __shared__ __align__(16) unsigned short vs[32*264];    // 16,896 B
    __shared__ __align__(16) unsigned short ps[4][16*72];  //  9,216 B

    const int tid = threadIdx.x;
    const int lane = tid & 63, w = tid >> 6;
    const int l15 = lane & 15, lq = lane >> 4;
    const int nb = blockIdx.x, bh = blockIdx.y;
    const int b = bh / HEADS, h = bh - b*HEADS;

    const unsigned short* qg = Q16 + ((size_t)b*N + nb*64)*C + h*32;
    const unsigned short* kg = K16 + (size_t)b*N*C + h*32;
    const unsigned short* vg = V16 + ((size_t)b*C + h*32)*N;

    const bf16x8 afrag = *(const bf16x8*)(qg + (size_t)(w*16 + l15)*C + lq*8);

    float sm[4] = {0.f, 0.f, 0.f, 0.f};
    f32x4 s[16];
    const f32x4 zero = {0.f, 0.f, 0.f, 0.f};

    // ------------------ PASS 1: row sums (no max; |s| bounded) ------------
    for (int ch = 0; ch < 4; ++ch) {
        __syncthreads();
        #pragma unroll
        for (int i = 0; i < 4; ++i) {
            int m = i*64 + (tid >> 2), c8 = (tid & 3) * 8;
            *(bf16x8*)(ks + m*40 + c8) = *(const bf16x8*)(kg + ((size_t)ch*256 + m)*C + c8);
        }
        __syncthreads();
        #pragma unroll
        for (int t = 0; t < 16; ++t) {
            bf16x8 bfrag = *(const bf16x8*)(ks + (16*t + l15)*40 + lq*8);
            s[t] = __builtin_amdgcn_mfma_f32_16x16x32_bf16(afrag, bfrag, zero, 0, 0, 0);
        }
        #pragma unroll
        for (int r = 0; r < 4; ++r) {
            float es = 0.f;
            #pragma unroll
            for (int t = 0; t < 16; ++t) es += __expf(s[t][r]);
            es += __shfl_xor(es, 1);
            es += __shfl_xor(es, 2);
            es += __shfl_xor(es, 4);
            es += __shfl_xor(es, 8);
            sm[r] += es;
        }
    }
    float lns[4];
    #pragma unroll
    for (int r = 0; r < 4; ++r) lns[r] = __logf(sm[r]);

    // ------------------ PASS 2: P write + PV ------------------
    f32x4 outf[2] = {zero, zero};
    unsigned short* pw = ps[w];
    float* arow = attn + ((size_t)bh*N + (size_t)nb*64 + w*16)*N;

    for (int ch = 0; ch < 4; ++ch) {
        __syncthreads();
        #pragma unroll
        for (int i = 0; i < 4; ++i) {
            int m = i*64 + (tid >> 2), c8 = (tid & 3) * 8;
            *(bf16x8*)(ks + m*40 + c8) = *(const bf16x8*)(kg + ((size_t)ch*256 + m)*C + c8);
        }
        #pragma unroll
        for (int i = 0; i < 4; ++i) {
            int u = tid + i*256;
            int cl = u >> 5, gg = u & 31;
            *(bf16x8*)(vs + cl*264 + gg*8) = *(const bf16x8*)(vg + (size_t)cl*N + ch*256 + gg*8);
        }
        __syncthreads();
        #pragma unroll
        for (int t = 0; t < 16; ++t) {
            bf16x8 bfrag = *(const bf16x8*)(ks + (16*t + l15)*40 + lq*8);
            s[t] = __builtin_amdgcn_mfma_f32_16x16x32_bf16(afrag, bfrag, zero, 0, 0, 0);
        }
        #pragma unroll
        for (int qr = 0; qr < 4; ++qr) {
            #pragma unroll
            for (int r = 0; r < 4; ++r) {
                int n_loc = 4*lq + r;
                float* ar = arow + (size_t)n_loc*N + ch*256 + qr*64;
                #pragma unroll
                for (int tt = 0; tt < 4; ++tt) {
                    float p = __expf(s[qr*4 + tt][r] - lns[r]);
                    int m_loc = 16*tt + l15;
                    ar[m_loc] = p;
                    pw[n_loc*72 + m_loc] = bf16_bits(p);
                }
            }
            __asm volatile("" ::: "memory");
            #pragma unroll
            for (int kk = 0; kk < 2; ++kk) {
                bf16x8 pa = *(const bf16x8*)(pw + l15*72 + kk*32 + lq*8);
                #pragma unroll
                for (int ct = 0; ct < 2; ++ct) {
                    bf16x8 vb = *(const bf16x8*)(vs + (16*ct + l15)*264 + qr*64 + kk*32 + lq*8);
                    outf[ct] = __builtin_amdgcn_mfma_f32_16x16x32_bf16(pa, vb, outf[ct], 0, 0, 0);
                }
            }
            __asm volatile("" ::: "memory");
        }
    }

    // write PV tile token-major bf16 via per-wave LDS repack
    float* sc = (float*)pw;   // [16n][33c]
    #pragma unroll
    for (int ct = 0; ct < 2; ++ct)
        #pragma unroll
        for (int r = 0; r < 4; ++r)
            sc[(4*lq + r)*33 + ct*16 + l15] = outf[ct][r];
    __asm volatile("" ::: "memory");
    {
        int n = lane >> 2, c8 = (lane & 3) * 8;
        bf16x8 v;
        #pragma unroll
        for (int j = 0; j < 8; ++j)
            v[j] = (short)bf16_bits(sc[n*33 + c8 + j]);
        *(bf16x8*)(OT + ((size_t)b*N + nb*64 + w*16 + n)*C + h*32 + c8) = v;
    }
}

// ---------------------------------------------------------------------------
extern "C" void kernel_launch(void* const* d_in, const int* in_sizes, int n_in,
                              void* d_out, int out_size, void* d_ws, size_t ws_size,
                              hipStream_t stream)
{
    const float* x1  = (const float*)d_in[0];
    const float* x2  = (const float*)d_in[1];
    const float* wq  = (const float*)d_in[2];
    const float* bq  = (const float*)d_in[3];
    const float* wdw = (const float*)d_in[4];
    const float* bdw = (const float*)d_in[5];
    const float* wpw = (const float*)d_in[6];
    const float* bpw = (const float*)d_in[7];
    const float* wk  = (const float*)d_in[8];
    const float* bk  = (const float*)d_in[9];
    const float* wv  = (const float*)d_in[10];
    const float* bv  = (const float*)d_in[11];
    const float* wo  = (const float*)d_in[12];
    const float* bo  = (const float*)d_in[13];

    const size_t P = (size_t)B * C * N;          // 3,145,728 floats
    float* ws = (float*)d_ws;
    unsigned short* Q16   = (unsigned short*)ws;             // 0.5P
    float*          qspat = ws + P/2;                        // 1P fp32
    unsigned short* sampT = (unsigned short*)(ws + 3*P/2);   // 0.5P
    unsigned short* K16   = (unsigned short*)(ws + 2*P);     // 0.5P
    unsigned short* V16   = (unsigned short*)(ws + 5*P/2);   // 0.5P
    unsigned short* x1T   = (unsigned short*)(ws + 3*P);     // 0.5P, reused as OT
    unsigned short* OT    = x1T;
    float*          tbuf  = ws + 7*P/2;                      // 1P fp32
    float*          coords= ws + 9*P/2;                      // 98,304 floats
    unsigned short* w16   = (unsigned short*)(ws + 9*P/2 + 98304);
    unsigned short* w16q = w16;
    unsigned short* w16k = w16 + 147456;
    unsigned short* w16v = w16 + 2*147456;
    unsigned short* w16o = w16 + 3*147456;

    float* ybuf = (float*)d_out;                 // (B,C,H,W)
    float* attn = (float*)d_out + P;             // (B,HEADS,N,N)

    prep<<<dim3(1056), 256, 0, stream>>>(wq, wk, wv, wo, x1, w16, x1T);
    proj_mfma<3><<<dim3(16, 6, 8), 256, 0, stream>>>(x1T, w16q, bq, nullptr, Q16, qspat);
    dwconv_gelu<<<dim3(4, Cg, BG), 256, 0, stream>>>(qspat, wdw, bdw, tbuf);
    offset_grid<<<dim3(384), 256, 0, stream>>>(tbuf, wpw, bpw, coords);
    bilin_sample<<<dim3(16, BG), 256, 0, stream>>>(x2, coords, sampT);
    proj_kv<<<dim3(16, 6, 8), 256, 0, stream>>>(sampT, w16k, bk, w16v, bv, K16, V16);
    attn_fused<<<dim3(16, 96), 256, 0, stream>>>(Q16, K16, V16, attn, OT);
    proj_mfma<2><<<dim3(16, 6, 8), 256, 0, stream>>>(OT, w16o, bo, x1, ybuf, nullptr);
}